// Round 1
// baseline (1634.838 us; speedup 1.0000x reference)
//
#include <hip/hip_runtime.h>

// CutoutColor: out[n,c,h,w] = (h in [top_n, top_n+28) && w in [left_n, left_n+28))
//                             ? colors[n,c] : x[n,c,h,w]
// N=4096, C=9, H=W=84, PATCH=28. Pure memory-bound elementwise masked fill.
// Layout: one block per (n,c) plane; per-block scalars (top/left/color) are
// wave-uniform. 84 floats/row = 21 float4 -> fully vectorized 16B/lane access.

#define CC_N 4096
#define CC_C 9
#define CC_H 84
#define CC_W 84
#define CC_PATCH 28
#define CC_W4 (CC_W / 4)            // 21 float4 per row
#define CC_PLANE4 (CC_H * CC_W4)    // 1764 float4 per (n,c) plane

__global__ __launch_bounds__(256) void CutoutColor_23519240913599_kernel(
    const float* __restrict__ x,
    const float* __restrict__ colors,
    const int*   __restrict__ tops,
    const int*   __restrict__ lefts,
    float* __restrict__ out)
{
    const int plane = blockIdx.x;          // = n*9 + c
    const int n     = plane / CC_C;
    const int top   = tops[n];
    const int left  = lefts[n];
    const float col = colors[plane];       // colors is [N,9] contiguous

    const float4* __restrict__ xp = (const float4*)(x   + (size_t)plane * (CC_H * CC_W));
    float4*       __restrict__ op = (float4*)      (out + (size_t)plane * (CC_H * CC_W));

    const int l0 = left;
    const int l1 = left + CC_PATCH;

    for (int i = threadIdx.x; i < CC_PLANE4; i += 256) {
        const int h  = i / CC_W4;          // compiler uses magic-mul for /21
        const int w  = (i - h * CC_W4) * 4;
        float4 v = xp[i];
        const bool rm = (h >= top) & (h < top + CC_PATCH);
        // branchless per-element column mask
        v.x = (rm & (w     >= l0) & (w     < l1)) ? col : v.x;
        v.y = (rm & (w + 1 >= l0) & (w + 1 < l1)) ? col : v.y;
        v.z = (rm & (w + 2 >= l0) & (w + 2 < l1)) ? col : v.z;
        v.w = (rm & (w + 3 >= l0) & (w + 3 < l1)) ? col : v.w;
        op[i] = v;
    }
}

extern "C" void kernel_launch(void* const* d_in, const int* in_sizes, int n_in,
                              void* d_out, int out_size, void* d_ws, size_t ws_size,
                              hipStream_t stream) {
    const float* x      = (const float*)d_in[0];
    const float* colors = (const float*)d_in[1];
    const int*   tops   = (const int*)d_in[2];
    const int*   lefts  = (const int*)d_in[3];
    float* out          = (float*)d_out;

    const int grid = CC_N * CC_C;          // 36864 planes
    CutoutColor_23519240913599_kernel<<<grid, 256, 0, stream>>>(x, colors, tops, lefts, out);
}